// Round 3
// baseline (1146.692 us; speedup 1.0000x reference)
//
#include <hip/hip_runtime.h>
#include <math.h>

// DotAttention: context[b,f] = sum_t softmax_t(<hd[b],he[b,t]>) * he[b,t,f]
// Single fused kernel: flash-style one-pass over he (512 MiB > L3, read once,
// async global->LDS staging), then the LAST block per batch (device-scope
// atomic counter) combines the S chunk-partials and writes the output.

#define BB 64
#define TT 2048
#define FF 1024
#define RR 4          // rows per tile (4 KiB each -> 16 KiB tile, double-buffered)

typedef __attribute__((address_space(1))) const void* gas_ptr;
typedef __attribute__((address_space(3))) void* las_ptr;

// async 16B-per-lane global->LDS: LDS dest = uniform base + lane*16
__device__ __forceinline__ void gld_lds16(const float* g, float* l) {
    __builtin_amdgcn_global_load_lds((gas_ptr)g, (las_ptr)l, 16, 0, 0);
}

__global__ __launch_bounds__(256) void attn_fused(
    const float* __restrict__ hd, const float* __restrict__ he,
    float* __restrict__ part_ctx, float* __restrict__ part_m,
    float* __restrict__ part_l, int* __restrict__ counters,
    float* __restrict__ out, int S, int Tc)
{
    const int bid  = blockIdx.x;
    const int b    = bid / S;
    const int s    = bid - b * S;
    const int t0   = s * Tc;
    const int lane = threadIdx.x & 63;
    const int wave = threadIdx.x >> 6;
    const int nt   = Tc / RR;

    __shared__ float buf[2][RR * FF];   // 2 x 16 KiB
    __shared__ int is_last;

    // hd[b] fragment matching the dot read layout: elements 4*lane + 256*k
    const float* hdb = hd + (size_t)b * FF;
    float4 hdv[4];
#pragma unroll
    for (int k = 0; k < 4; ++k)
        hdv[k] = *(const float4*)(hdb + 4 * lane + 256 * k);

    const float* heb = he + ((size_t)b * TT + t0) * (size_t)FF;

    float m = -INFINITY, l = 0.f;
    float4 ctx = make_float4(0.f, 0.f, 0.f, 0.f);

    // prologue: stage tile 0 into buf[0] (wave w stages row w, 4 x 1 KiB)
    {
        const float* row = heb + (size_t)wave * FF;
#pragma unroll
        for (int k = 0; k < 4; ++k)
            gld_lds16(row + k * 256 + lane * 4, &buf[0][wave * FF + k * 256]);
    }

    for (int kt = 0; kt < nt; ++kt) {
        const int cur = kt & 1;
        __syncthreads();   // drains vmcnt: tile kt staged; buf[cur^1] is dead

        // stage tile kt+1 into the dead buffer — overlaps the compute phase
        if (kt + 1 < nt) {
            const float* row = heb + ((size_t)(kt + 1) * RR + wave) * FF;
#pragma unroll
            for (int k = 0; k < 4; ++k)
                gld_lds16(row + k * 256 + lane * 4,
                          &buf[cur ^ 1][wave * FF + k * 256]);
        }

        // all RR row-dots, redundantly per wave (no score-sharing barrier)
        float d[RR];
#pragma unroll
        for (int r = 0; r < RR; ++r) {
            float4 hv[4];
#pragma unroll
            for (int k = 0; k < 4; ++k)
                hv[k] = *(const float4*)&buf[cur][r * FF + 4 * lane + 256 * k];
            float acc = 0.f;
#pragma unroll
            for (int k = 0; k < 4; ++k)
                acc += hdv[k].x * hv[k].x + hdv[k].y * hv[k].y +
                       hdv[k].z * hv[k].z + hdv[k].w * hv[k].w;
            d[r] = acc;
        }
        // RR independent butterflies, interleaved for DS-latency ILP
#pragma unroll
        for (int off = 32; off >= 1; off >>= 1) {
#pragma unroll
            for (int r = 0; r < RR; ++r)
                d[r] += __shfl_xor(d[r], off, 64);
        }

        // block-wide online softmax update (identical in every thread)
        float mn = m;
#pragma unroll
        for (int r = 0; r < RR; ++r) mn = fmaxf(mn, d[r]);
        const float alpha = __expf(m - mn);   // exp(-inf)=0 on first tile
        float w[RR], wsum = 0.f;
#pragma unroll
        for (int r = 0; r < RR; ++r) { w[r] = __expf(d[r] - mn); wsum += w[r]; }

        // accumulate this thread's 4-float f-slice
        const int f4 = threadIdx.x * 4;
        float4 a = make_float4(ctx.x * alpha, ctx.y * alpha,
                               ctx.z * alpha, ctx.w * alpha);
#pragma unroll
        for (int r = 0; r < RR; ++r) {
            const float4 rv = *(const float4*)&buf[cur][r * FF + f4];
            a.x += w[r] * rv.x; a.y += w[r] * rv.y;
            a.z += w[r] * rv.z; a.w += w[r] * rv.w;
        }
        ctx = a;
        l = l * alpha + wsum;
        m = mn;
    }

    // publish this block's partial
    *(float4*)(part_ctx + (size_t)bid * FF + threadIdx.x * 4) = ctx;
    if (threadIdx.x == 0) { part_m[bid] = m; part_l[bid] = l; }

    // last block per batch combines (device-scope atomic; counters pre-zeroed)
    __threadfence();
    if (threadIdx.x == 0)
        is_last = (atomicAdd(&counters[b], 1) == S - 1) ? 1 : 0;
    __syncthreads();
    if (!is_last) return;
    __threadfence();   // acquire: make all S partials visible

    float M = -INFINITY;
    for (int p = 0; p < S; ++p) M = fmaxf(M, part_m[b * S + p]);
    float L = 0.f;
    for (int p = 0; p < S; ++p)
        L += part_l[b * S + p] * __expf(part_m[b * S + p] - M);

    const int f4 = threadIdx.x * 4;
    float4 acc = make_float4(0.f, 0.f, 0.f, 0.f);
    for (int p = 0; p < S; ++p) {
        const float e  = __expf(part_m[b * S + p] - M);
        const float4 c = *(const float4*)(part_ctx + ((size_t)(b * S + p)) * FF + f4);
        acc.x += e * c.x; acc.y += e * c.y; acc.z += e * c.z; acc.w += e * c.w;
    }
    const float inv = 1.f / L;
    float4 o = make_float4(acc.x * inv, acc.y * inv, acc.z * inv, acc.w * inv);
    *(float4*)(out + (size_t)b * FF + f4) = o;
}

extern "C" void kernel_launch(void* const* d_in, const int* in_sizes, int n_in,
                              void* d_out, int out_size, void* d_ws, size_t ws_size,
                              hipStream_t stream) {
    const float* hd = (const float*)d_in[0];   // (64, 1024) f32
    const float* he = (const float*)d_in[1];   // (64, 2048, 1024) f32
    float* out = (float*)d_out;                // (64, 1024) f32

    // largest split count whose partials + counters fit in the workspace
    int S = 32;
    while (S > 1 &&
           (size_t)BB * S * (FF + 2) * sizeof(float) + BB * sizeof(int) > ws_size)
        S >>= 1;
    const int Tc = TT / S;   // 64 at S=32 -> 16 tiles of RR=4

    float* part_ctx = (float*)d_ws;                      // B*S*F
    float* part_m   = part_ctx + (size_t)BB * S * FF;    // B*S
    float* part_l   = part_m + (size_t)BB * S;           // B*S
    int*   counters = (int*)(part_l + (size_t)BB * S);   // B

    // ws is poisoned 0xAA before every call — zero the counters (capture-legal)
    hipMemsetAsync(counters, 0, BB * sizeof(int), stream);

    attn_fused<<<BB * S, 256, 0, stream>>>(hd, he, part_ctx, part_m, part_l,
                                           counters, out, S, Tc);
}